// Round 1
// baseline (187.292 us; speedup 1.0000x reference)
//
#include <hip/hip_runtime.h>
#include <math.h>

#define N_RAYS 65536
#define LAMBDA_OPACITY 0.001f
#define LAMBDA_DISTORTION 0.001f
#define RAYS_PER_BLOCK 4

// One 64-lane wave per ray. 192 samples/ray = 3 coalesced chunks of 64.
// Exclusive prefix sums of w and w*t via in-wave shuffle scan + cross-chunk carry.
__global__ __launch_bounds__(RAYS_PER_BLOCK * 64)
void nerf_loss_kernel(
    const float* __restrict__ rgb_coarse,
    const float* __restrict__ rgb_fine,
    const float* __restrict__ rgb_target,
    const float* __restrict__ depth,
    const float* __restrict__ depth_target,
    const float* __restrict__ opacity,
    const float* __restrict__ ws,
    const float* __restrict__ deltas,
    const float* __restrict__ ts,
    const int*   __restrict__ rays_a,
    float* __restrict__ out)
{
    const int wave = threadIdx.x >> 6;
    const int lane = threadIdx.x & 63;
    const int ray  = blockIdx.x * RAYS_PER_BLOCK + wave;
    if (ray >= N_RAYS) return;

    const int out_ray = rays_a[ray * 3 + 0];
    const int start   = rays_a[ray * 3 + 1];
    const int count   = rays_a[ray * 3 + 2];   // 192 in this setup

    float carry_w = 0.f, carry_wt = 0.f, acc = 0.f;

    for (int chunk_base = 0; chunk_base < count; chunk_base += 64) {
        const int idx   = chunk_base + lane;
        const bool ok   = idx < count;
        const int  p    = start + idx;
        const float w   = ok ? ws[p]     : 0.f;
        const float t   = ok ? ts[p]     : 0.f;
        const float d   = ok ? deltas[p] : 0.f;
        const float wt  = w * t;

        // inclusive wave scan of (w, wt)
        float iw = w, iwt = wt;
        #pragma unroll
        for (int off = 1; off < 64; off <<= 1) {
            float nw  = __shfl_up(iw,  off, 64);
            float nwt = __shfl_up(iwt, off, 64);
            if (lane >= off) { iw += nw; iwt += nwt; }
        }

        const float excl_w  = carry_w  + (iw  - w);
        const float excl_wt = carry_wt + (iwt - wt);
        acc += 2.f * w * (t * excl_w - excl_wt) + w * w * d * (1.f / 3.f);

        carry_w  += __shfl(iw,  63, 64);
        carry_wt += __shfl(iwt, 63, 64);
    }

    // wave reduction of acc
    #pragma unroll
    for (int off = 32; off > 0; off >>= 1)
        acc += __shfl_down(acc, off, 64);

    if (lane == 0) {
        out[3 * N_RAYS + out_ray] = LAMBDA_DISTORTION * acc;

        const float rt0 = rgb_target[ray * 3 + 0];
        const float rt1 = rgb_target[ray * 3 + 1];
        const float rt2 = rgb_target[ray * 3 + 2];
        const float c0 = rgb_coarse[ray * 3 + 0] - rt0;
        const float c1 = rgb_coarse[ray * 3 + 1] - rt1;
        const float c2 = rgb_coarse[ray * 3 + 2] - rt2;
        const float f0 = rgb_fine[ray * 3 + 0] - rt0;
        const float f1 = rgb_fine[ray * 3 + 1] - rt1;
        const float f2 = rgb_fine[ray * 3 + 2] - rt2;
        out[ray] = (c0 * c0 + c1 * c1 + c2 * c2) * (1.f / 3.f)
                 + (f0 * f0 + f1 * f1 + f2 * f2) * (1.f / 3.f);

        out[N_RAYS + ray] = fabsf(depth[ray] - depth_target[ray]);

        const float o = opacity[ray] + 1e-10f;
        out[2 * N_RAYS + ray] = LAMBDA_OPACITY * (-o * logf(o));
    }
}

extern "C" void kernel_launch(void* const* d_in, const int* in_sizes, int n_in,
                              void* d_out, int out_size, void* d_ws, size_t ws_size,
                              hipStream_t stream) {
    const float* rgb_coarse   = (const float*)d_in[0];
    const float* rgb_fine     = (const float*)d_in[1];
    const float* rgb_target   = (const float*)d_in[2];
    const float* depth        = (const float*)d_in[3];
    const float* depth_target = (const float*)d_in[4];
    const float* opacity      = (const float*)d_in[5];
    const float* ws           = (const float*)d_in[6];
    const float* deltas       = (const float*)d_in[7];
    const float* ts           = (const float*)d_in[8];
    const int*   rays_a       = (const int*)d_in[9];
    float* out = (float*)d_out;

    const int grid = (N_RAYS + RAYS_PER_BLOCK - 1) / RAYS_PER_BLOCK;
    nerf_loss_kernel<<<grid, RAYS_PER_BLOCK * 64, 0, stream>>>(
        rgb_coarse, rgb_fine, rgb_target, depth, depth_target, opacity,
        ws, deltas, ts, rays_a, out);
}

// Round 2
// 179.959 us; speedup vs baseline: 1.0407x; 1.0407x over previous
//
#include <hip/hip_runtime.h>
#include <math.h>

#define N_RAYS 65536
#define LAMBDA_OPACITY 0.001f
#define LAMBDA_DISTORTION 0.001f
#define RAYS_PER_BLOCK 4

// ---------------------------------------------------------------------------
// Distortion kernel: one 64-lane wave per ray, lane j owns contiguous samples
// [3j, 3j+3). Lane-local exclusive scan is sequential FMAs; one wave-level
// exclusive scan (6 shfl steps) replaces the previous 3 serialized chunk
// scans + carry chain.
// ---------------------------------------------------------------------------
__global__ __launch_bounds__(RAYS_PER_BLOCK * 64)
void distortion_kernel(
    const float* __restrict__ ws,
    const float* __restrict__ deltas,
    const float* __restrict__ ts,
    const int*   __restrict__ rays_a,
    float* __restrict__ out)
{
    const int wave = threadIdx.x >> 6;
    const int lane = threadIdx.x & 63;
    const int ray  = blockIdx.x * RAYS_PER_BLOCK + wave;
    if (ray >= N_RAYS) return;

    const int out_ray = rays_a[ray * 3 + 0];
    const int start   = rays_a[ray * 3 + 1];
    const int count   = rays_a[ray * 3 + 2];   // 192 in this setup

    // lane-local contiguous segment of up to 3 samples
    const int s0 = 3 * lane;
    const int p  = start + s0;
    const bool ok0 = (s0 + 0) < count;
    const bool ok1 = (s0 + 1) < count;
    const bool ok2 = (s0 + 2) < count;

    const float w0 = ok0 ? ws[p + 0] : 0.f;
    const float w1 = ok1 ? ws[p + 1] : 0.f;
    const float w2 = ok2 ? ws[p + 2] : 0.f;
    const float t0 = ok0 ? ts[p + 0] : 0.f;
    const float t1 = ok1 ? ts[p + 1] : 0.f;
    const float t2 = ok2 ? ts[p + 2] : 0.f;
    const float d0 = ok0 ? deltas[p + 0] : 0.f;
    const float d1 = ok1 ? deltas[p + 1] : 0.f;
    const float d2 = ok2 ? deltas[p + 2] : 0.f;

    const float wt0 = w0 * t0, wt1 = w1 * t1, wt2 = w2 * t2;

    // lane totals
    const float lw  = w0 + w1 + w2;
    const float lwt = wt0 + wt1 + wt2;

    // wave-level inclusive scan of lane totals (two independent chains,
    // interleaved for latency hiding)
    float iw = lw, iwt = lwt;
    #pragma unroll
    for (int off = 1; off < 64; off <<= 1) {
        float nw  = __shfl_up(iw,  off, 64);
        float nwt = __shfl_up(iwt, off, 64);
        if (lane >= off) { iw += nw; iwt += nwt; }
    }

    // exclusive base for this lane's segment
    float e_w  = iw  - lw;
    float e_wt = iwt - lwt;

    // lane-local sequential exclusive accumulation
    float acc;
    acc  = 2.f * w0 * (t0 * e_w - e_wt) + w0 * w0 * d0 * (1.f / 3.f);
    e_w += w0; e_wt += wt0;
    acc += 2.f * w1 * (t1 * e_w - e_wt) + w1 * w1 * d1 * (1.f / 3.f);
    e_w += w1; e_wt += wt1;
    acc += 2.f * w2 * (t2 * e_w - e_wt) + w2 * w2 * d2 * (1.f / 3.f);

    // wave reduction of acc
    #pragma unroll
    for (int off = 32; off > 0; off >>= 1)
        acc += __shfl_down(acc, off, 64);

    if (lane == 0)
        out[3 * N_RAYS + out_ray] = LAMBDA_DISTORTION * acc;
}

// ---------------------------------------------------------------------------
// Per-ray cheap terms: 1 thread per ray, fully coalesced.
// ---------------------------------------------------------------------------
__global__ __launch_bounds__(256)
void perray_kernel(
    const float* __restrict__ rgb_coarse,
    const float* __restrict__ rgb_fine,
    const float* __restrict__ rgb_target,
    const float* __restrict__ depth,
    const float* __restrict__ depth_target,
    const float* __restrict__ opacity,
    float* __restrict__ out)
{
    const int r = blockIdx.x * blockDim.x + threadIdx.x;
    if (r >= N_RAYS) return;

    const float rt0 = rgb_target[r * 3 + 0];
    const float rt1 = rgb_target[r * 3 + 1];
    const float rt2 = rgb_target[r * 3 + 2];
    const float c0 = rgb_coarse[r * 3 + 0] - rt0;
    const float c1 = rgb_coarse[r * 3 + 1] - rt1;
    const float c2 = rgb_coarse[r * 3 + 2] - rt2;
    const float f0 = rgb_fine[r * 3 + 0] - rt0;
    const float f1 = rgb_fine[r * 3 + 1] - rt1;
    const float f2 = rgb_fine[r * 3 + 2] - rt2;

    out[r] = (c0 * c0 + c1 * c1 + c2 * c2) * (1.f / 3.f)
           + (f0 * f0 + f1 * f1 + f2 * f2) * (1.f / 3.f);

    out[N_RAYS + r] = fabsf(depth[r] - depth_target[r]);

    const float o = opacity[r] + 1e-10f;
    out[2 * N_RAYS + r] = LAMBDA_OPACITY * (-o * logf(o));
}

extern "C" void kernel_launch(void* const* d_in, const int* in_sizes, int n_in,
                              void* d_out, int out_size, void* d_ws, size_t ws_size,
                              hipStream_t stream) {
    const float* rgb_coarse   = (const float*)d_in[0];
    const float* rgb_fine     = (const float*)d_in[1];
    const float* rgb_target   = (const float*)d_in[2];
    const float* depth        = (const float*)d_in[3];
    const float* depth_target = (const float*)d_in[4];
    const float* opacity      = (const float*)d_in[5];
    const float* ws           = (const float*)d_in[6];
    const float* deltas       = (const float*)d_in[7];
    const float* ts           = (const float*)d_in[8];
    const int*   rays_a       = (const int*)d_in[9];
    float* out = (float*)d_out;

    const int grid_d = (N_RAYS + RAYS_PER_BLOCK - 1) / RAYS_PER_BLOCK;
    distortion_kernel<<<grid_d, RAYS_PER_BLOCK * 64, 0, stream>>>(
        ws, deltas, ts, rays_a, out);

    perray_kernel<<<N_RAYS / 256, 256, 0, stream>>>(
        rgb_coarse, rgb_fine, rgb_target, depth, depth_target, opacity, out);
}